// Round 1
// baseline (615.003 us; speedup 1.0000x reference)
//
#include <hip/hip_runtime.h>
#include <math.h>

#define HID   128
#define ROWS  64
#define TPB   512

__global__ __launch_bounds__(TPB, 1)
void stress_kernel(const float* __restrict__ F,
                   const float* __restrict__ W1, const float* __restrict__ b1,
                   const float* __restrict__ W2, const float* __restrict__ b2,
                   const float* __restrict__ W3, const float* __restrict__ b3,
                   float* __restrict__ out, int N)
{
    // LDS layout (~108 KB total -> 1 block/CU)
    __shared__ __align__(16) float sW2[HID * HID];   // 64 KB, [k][j]
    __shared__ __align__(16) float sU[ROWS * 132];   // union: h1T [128][64] (8192 f) then h2 [64][132] (8448 f)
    __shared__ __align__(16) float sW1[3 * HID];
    __shared__ __align__(16) float sb1[HID];
    __shared__ __align__(16) float sb2[HID];
    __shared__ __align__(16) float sW3[HID * 4];
    __shared__ __align__(16) float sb3[4];
    __shared__ __align__(16) float sF[ROWS * 4];
    __shared__ __align__(16) float sR[ROWS * 4];
    __shared__ __align__(16) float sX[ROWS * 3];
    __shared__ __align__(16) float sY[ROWS * 4];

    const int tid = threadIdx.x;

    // ---- stage weights once per block ----
    for (int i = tid; i < HID * HID / 4; i += TPB)
        ((float4*)sW2)[i] = ((const float4*)W2)[i];
    for (int i = tid; i < 3 * HID; i += TPB) sW1[i] = W1[i];
    for (int i = tid; i < HID; i += TPB) { sb1[i] = b1[i]; sb2[i] = b2[i]; }
    for (int i = tid; i < HID * 4; i += TPB) sW3[i] = W3[i];
    if (tid < 4) sb3[tid] = b3[tid];
    __syncthreads();

    // layer-2 register tile: 4 rows x 4 cols per thread
    const int rg = tid >> 5;        // 0..15 row-group
    const int jg = tid & 31;        // 0..31 col-group
    const int r0 = rg << 2;
    const int j0 = jg << 2;

    const int nTiles = (N + ROWS - 1) / ROWS;
    for (int tile = blockIdx.x; tile < nTiles; tile += gridDim.x) {
        const int row0 = tile * ROWS;

        // ---- Phase A: invariants + polar rotation (threads 0..63) ----
        if (tid < ROWS) {
            const int n = row0 + tid;
            float a = 0.f, b = 0.f, c = 0.f, d = 0.f;
            if (n < N) {
                float4 f = ((const float4*)F)[n];
                a = f.x; b = f.y; c = f.z; d = f.w;
            }
            float J   = a * d - b * c;
            float ss  = a * a + b * b + c * c + d * d;
            float sgn = (J >= 0.f) ? 1.f : -1.f;
            float r   = sqrtf(fmaxf(ss + 2.f * fabsf(J), 1e-30f)); // sigma1+sigma2
            float inv = 1.f / r;
            sX[tid * 3 + 0] = r - 2.f;    // I1
            sX[tid * 3 + 1] = ss - 1.f;   // I2
            sX[tid * 3 + 2] = J - 1.f;    // I3
            // R = (F + sgn(J) * adj(F)^T) / r  — the polar factor U@Vh
            sR[tid * 4 + 0] = (a + sgn * d) * inv;
            sR[tid * 4 + 1] = (b - sgn * c) * inv;
            sR[tid * 4 + 2] = (c - sgn * b) * inv;
            sR[tid * 4 + 3] = (d + sgn * a) * inv;
            sF[tid * 4 + 0] = a; sF[tid * 4 + 1] = b;
            sF[tid * 4 + 2] = c; sF[tid * 4 + 3] = d;
        }
        __syncthreads();

        // ---- Phase B: layer1  h1T[k][row] = relu(b1[k] + sum_i x[i]*W1[i][k]) ----
        for (int i = tid; i < ROWS * HID; i += TPB) {
            int k = i >> 6, rr = i & 63;
            float v = sb1[k]
                    + sX[rr * 3 + 0] * sW1[k]
                    + sX[rr * 3 + 1] * sW1[HID + k]
                    + sX[rr * 3 + 2] * sW1[2 * HID + k];
            sU[i] = fmaxf(v, 0.f);   // sU[k*64 + rr]
        }
        __syncthreads();

        // ---- Phase C: layer2  h2[r][j] = relu(b2[j] + sum_k h1[r][k]*W2[k][j]) ----
        float acc[4][4] = {};
        {
            const float* pH = sU + r0;     // h1T: [k][64]
            const float* pW = sW2 + j0;    // W2:  [k][128]
            #pragma unroll 8
            for (int k = 0; k < HID; ++k) {
                float4 hv = *(const float4*)(pH + k * ROWS);
                float4 wv = *(const float4*)(pW + k * HID);
                float h[4] = { hv.x, hv.y, hv.z, hv.w };
                float w[4] = { wv.x, wv.y, wv.z, wv.w };
                #pragma unroll
                for (int i = 0; i < 4; ++i)
                    #pragma unroll
                    for (int t = 0; t < 4; ++t)
                        acc[i][t] += h[i] * w[t];
            }
        }
        __syncthreads();   // everyone done reading h1T before overwriting sU with h2

        #pragma unroll
        for (int i = 0; i < 4; ++i) {
            float4 o;
            o.x = fmaxf(acc[i][0] + sb2[j0 + 0], 0.f);
            o.y = fmaxf(acc[i][1] + sb2[j0 + 1], 0.f);
            o.z = fmaxf(acc[i][2] + sb2[j0 + 2], 0.f);
            o.w = fmaxf(acc[i][3] + sb2[j0 + 3], 0.f);
            *(float4*)(sU + (r0 + i) * 132 + j0) = o;  // h2, padded stride 132
        }
        __syncthreads();

        // ---- Phase D: layer3  y[row][t] = b3[t] + sum_j h2[row][j]*W3[j][t] ----
        if (tid < ROWS * 4) {
            int rr = tid >> 2, t = tid & 3;
            float a3 = sb3[t];
            const float* ph2 = sU + rr * 132;
            #pragma unroll 4
            for (int j = 0; j < HID; ++j)
                a3 += ph2[j] * sW3[j * 4 + t];
            sY[tid] = a3;
        }
        __syncthreads();

        // ---- Phase E: symmetrize, P = R@S, cauchy = P@F^T, store ----
        if (tid < ROWS) {
            const int n = row0 + tid;
            if (n < N) {
                float y0 = sY[tid * 4 + 0], y1 = sY[tid * 4 + 1];
                float y2 = sY[tid * 4 + 2], y3 = sY[tid * 4 + 3];
                float s01 = 0.5f * (y1 + y2);
                float R00 = sR[tid * 4 + 0], R01 = sR[tid * 4 + 1];
                float R10 = sR[tid * 4 + 2], R11 = sR[tid * 4 + 3];
                float P00 = R00 * y0  + R01 * s01;
                float P01 = R00 * s01 + R01 * y3;
                float P10 = R10 * y0  + R11 * s01;
                float P11 = R10 * s01 + R11 * y3;
                float a = sF[tid * 4 + 0], b = sF[tid * 4 + 1];
                float c = sF[tid * 4 + 2], d = sF[tid * 4 + 3];
                float4 o;
                o.x = P00 * a + P01 * b;   // C[i][k] = sum_j P[i][j] F[k][j]
                o.y = P00 * c + P01 * d;
                o.z = P10 * a + P11 * b;
                o.w = P10 * c + P11 * d;
                ((float4*)out)[n] = o;
            }
        }
        __syncthreads();   // protect sF/sR/sX/sY before next tile
    }
}

extern "C" void kernel_launch(void* const* d_in, const int* in_sizes, int n_in,
                              void* d_out, int out_size, void* d_ws, size_t ws_size,
                              hipStream_t stream) {
    const float* F  = (const float*)d_in[0];
    const float* W1 = (const float*)d_in[1];
    const float* b1 = (const float*)d_in[2];
    const float* W2 = (const float*)d_in[3];
    const float* b2 = (const float*)d_in[4];
    const float* W3 = (const float*)d_in[5];
    const float* b3 = (const float*)d_in[6];
    float* out = (float*)d_out;
    const int N = in_sizes[0] / 4;

    stress_kernel<<<dim3(512), dim3(TPB), 0, stream>>>(F, W1, b1, W2, b2, W3, b3, out, N);
}